// Round 3
// baseline (289.031 us; speedup 1.0000x reference)
//
#include <hip/hip_runtime.h>
#include <math.h>

#define BB 8
#define NN 40000
#define CC 80
#define TOPK 500
#define MM (BB*TOPK)          // 4000
#define NBINS 16384
#define BIN_LO (-8.0f)
#define BIN_SCALE 1024.0f     // bins per unit -> covers [-8, 8)
#define CAP 4096
#define NGROUPS (CC*BB)       // 640
#define THR_CONF_F 0.05f
#define THR_NMS_F 0.5f

__device__ __forceinline__ int bin_of(float x){
  float f = (x - BIN_LO) * BIN_SCALE;
  int b = (int)floorf(f);
  b = b < 0 ? 0 : b;
  b = b > (NBINS-1) ? (NBINS-1) : b;
  return b;
}

// Kernel 1: 4 lanes per row. Lane-group reads one contiguous 64B line per
// instruction (perfect coalescing), 5 independent float4 loads per thread.
// Cross-lane argmax combine keeps first-max semantics via (==,idx<) tie-break.
__global__ void k_score(const float* __restrict__ pconf,
                        float* __restrict__ logitv, int* __restrict__ label,
                        int* __restrict__ hist){
  int g   = blockIdx.x*256 + threadIdx.x;   // 1.28M threads total
  int row = g >> 2;
  int sub = g & 3;
  const float4* p = (const float4*)pconf + (size_t)row*20 + sub;
  float4 v0 = p[0], v1 = p[4], v2 = p[8], v3 = p[12], v4 = p[16];
  float best = -3.4e38f; int bi = 0;
  int c0 = sub*4;
  #define CHK(vv,it) { \
    int base = c0 + (it)*16; \
    if(vv.x>best){best=vv.x;bi=base+0;} \
    if(vv.y>best){best=vv.y;bi=base+1;} \
    if(vv.z>best){best=vv.z;bi=base+2;} \
    if(vv.w>best){best=vv.w;bi=base+3;} }
  CHK(v0,0) CHK(v1,1) CHK(v2,2) CHK(v3,3) CHK(v4,4)
  #undef CHK
  // combine across the 4-lane group (xor 1, xor 2 stay within aligned quad)
  #pragma unroll
  for(int d=1; d<4; d<<=1){
    float ov = __shfl_xor(best, d, 64);
    int   oi = __shfl_xor(bi,   d, 64);
    if(ov > best || (ov == best && oi < bi)){ best = ov; bi = oi; }
  }
  if(sub == 0){
    logitv[row] = best; label[row] = bi;
    atomicAdd(&hist[(row/NN)*NBINS + bin_of(best)], 1);
  }
}

// Kernel 2: per-batch threshold bin (suffix count >= TOPK), 4-bin safety margin.
__global__ void k_thresh(const int* __restrict__ hist, int* __restrict__ tbin){
  int b = blockIdx.x;
  __shared__ int csum[256];
  int c = threadIdx.x;
  int s = 0;
  for(int i=0;i<64;i++) s += hist[b*NBINS + c*64 + i];
  csum[c] = s;
  __syncthreads();
  if(c==0){
    int cum = 0;
    for(int cc2=255; cc2>=0; cc2--){
      if(cum + csum[cc2] >= TOPK){
        int cum2 = cum; int t = 0;
        for(int bb2=cc2*64+63; bb2>=cc2*64; bb2--){
          cum2 += hist[b*NBINS+bb2];
          if(cum2 >= TOPK){ t = bb2; break; }
        }
        int tt = t - 4; if(tt < 0) tt = 0;
        tbin[b] = tt;
        return;
      }
      cum += csum[cc2];
    }
    tbin[b] = 0;
  }
}

// Kernel 3: compact candidates (bin >= threshold). Correctly-rounded f32 sigmoid
// (double exp) computed only for selected rows (~510/batch). Key layout:
// bits[48:16] = sigmoid f32 bits (positive -> unsigned-monotone),
// bits[15:0]  = 65535-idx  => descending sort = score desc, index asc
// == jax.lax.top_k ordering incl. f32 tie groups.
__global__ void k_compact(const float* __restrict__ logitv,
                          const int* __restrict__ tbin, int* __restrict__ cnt,
                          unsigned long long* __restrict__ cand){
  int row = blockIdx.x*256 + threadIdx.x;
  if(row >= BB*NN) return;
  int b = row / NN;
  float lg = logitv[row];
  if(bin_of(lg) >= tbin[b]){
    int pos = atomicAdd(&cnt[b], 1);
    if(pos < CAP){
      float t = (float)exp(-(double)lg);   // correctly-rounded f32 exp(-x)
      float s = 1.0f/(1.0f+t);             // f32 add + f32 div
      unsigned int sb = __float_as_uint(s);
      int idx = row - b*NN;
      cand[(size_t)b*CAP + pos] =
        ((unsigned long long)sb << 16) | (unsigned long long)(65535 - idx);
    }
  }
}

// Kernel 4: O(n^2) rank-and-emit. Keys unique -> rank is a permutation; thread
// with rank<500 emits to output slot 'rank' directly.
__global__ void __launch_bounds__(512)
k_rankemit(const unsigned long long* __restrict__ cand, const int* __restrict__ cnt,
           const int* __restrict__ label, const float* __restrict__ pboxes,
           float* __restrict__ out,
           float* __restrict__ cbox, int* __restrict__ cgid,
           float* __restrict__ cscore, int* __restrict__ maxbits){
  int b = blockIdx.x;
  __shared__ unsigned long long keys[CAP];
  int n = cnt[b]; if(n > CAP) n = CAP;
  for(int i=threadIdx.x; i<n; i+=512) keys[i] = cand[(size_t)b*CAP + i];
  __syncthreads();
  for(int i=threadIdx.x; i<n; i+=512){
    unsigned long long ki = keys[i];
    int rank = 0;
    for(int j=0; j<n; j++) rank += (keys[j] > ki) ? 1 : 0;
    if(rank < TOPK){
      int idx = 65535 - (int)(ki & 0xFFFFULL);
      int row = b*NN + idx;
      float s = __uint_as_float((unsigned int)(ki >> 16));
      int lab = label[row];
      float4 bv = *(const float4*)(pboxes + (size_t)row*4);
      int m = b*TOPK + rank;
      out[m] = (float)b;                       // ids_batch1
      float* ob = out + MM + (size_t)m*4;      // p_boxes1
      ob[0]=bv.x; ob[1]=bv.y; ob[2]=bv.z; ob[3]=bv.w;
      out[5*MM + m] = (float)lab;              // p_labels1
      out[6*MM + m] = s;                       // p_scores1
      cbox[m*4+0]=bv.x; cbox[m*4+1]=bv.y; cbox[m*4+2]=bv.z; cbox[m*4+3]=bv.w;
      cgid[m] = lab*BB + b;                    // ref key = label*B + batch
      cscore[m] = s;
      float mx = fmaxf(fmaxf(bv.x,bv.y), fmaxf(bv.z,bv.w));
      atomicMax(maxbits, __float_as_int(mx));  // all-positive max -> int cmp ok
    }
  }
}

// Kernel 5: per-(label,batch)-group greedy NMS, one wave per group. Cross-group
// IoU is exactly 0 (offset gap >= 0.89), so global greedy == per-group greedy
// in within-group flat order (= per-batch score-desc, index-asc order).
__global__ void __launch_bounds__(64)
k_nms(const float* __restrict__ cbox, const int* __restrict__ cgid,
      const float* __restrict__ cscore, const int* __restrict__ maxbits,
      float* __restrict__ out_keep){
  int g = blockIdx.x;
  int lane = threadIdx.x;
  __shared__ float bx[TOPK][4];
  __shared__ float area[TOPK];
  __shared__ int   mid[TOPK];
  __shared__ unsigned char keepf[TOPK];
  float mc  = __int_as_float(*maxbits);
  float off = (float)g * (mc + 1.0f);

  int count = 0;
  for(int base=0; base<MM; base+=64){
    int m = base + lane;
    bool match = (m < MM) && (cgid[m] == g);
    unsigned long long mk = __ballot(match);
    if(match){
      int p = count + __popcll(mk & ((1ULL<<lane)-1ULL));
      if(p < TOPK){
        float x1 = cbox[m*4+0] + off;
        float y1 = cbox[m*4+1] + off;
        float x2 = cbox[m*4+2] + off;
        float y2 = cbox[m*4+3] + off;
        bx[p][0]=x1; bx[p][1]=y1; bx[p][2]=x2; bx[p][3]=y2;
        area[p] = (x2-x1)*(y2-y1);             // area of OFFSET box, like ref
        mid[p] = m;
        keepf[p] = (cscore[m] > THR_CONF_F) ? 1 : 0;
      }
    }
    count += __popcll(mk);
  }
  if(count > TOPK) count = TOPK;
  __syncthreads();

  for(int i=0; i<count; i++){
    if(keepf[i]){
      float ix1=bx[i][0], iy1=bx[i][1], ix2=bx[i][2], iy2=bx[i][3], ia=area[i];
      for(int j=i+1+lane; j<count; j+=64){
        if(keepf[j]){
          float lx = fmaxf(ix1, bx[j][0]);
          float ly = fmaxf(iy1, bx[j][1]);
          float rx = fminf(ix2, bx[j][2]);
          float ry = fminf(iy2, bx[j][3]);
          float w = fmaxf(rx-lx, 0.0f), h = fmaxf(ry-ly, 0.0f);
          float inter = w*h;
          float uni = ia + area[j] - inter;     // (a_i + a_j) - inter, ref order
          float iou = inter / fmaxf(uni, 1e-9f);
          if(iou > THR_NMS_F) keepf[j] = 0;
        }
      }
    }
    __syncthreads();
  }
  for(int p=lane; p<count; p+=64)
    out_keep[mid[p]] = keepf[p] ? 1.0f : 0.0f;
}

extern "C" void kernel_launch(void* const* d_in, const int* in_sizes, int n_in,
                              void* d_out, int out_size, void* d_ws, size_t ws_size,
                              hipStream_t stream) {
  const float* pconf  = (const float*)d_in[0];
  const float* pboxes = (const float*)d_in[1];
  float* out = (float*)d_out;
  char* ws = (char*)d_ws;

  // ws layout (bytes)
  int* hist    = (int*)(ws + 0);                 // 8*16384*4 = 524288
  int* cnt     = (int*)(ws + 524288);            // 8*4
  int* tbin    = (int*)(ws + 524320);            // 8*4
  int* maxbits = (int*)(ws + 524352);            // 4
  float* logitv  = (float*)(ws + 524416);        // 320000*4 = 1280000
  int*   label   = (int*)  (ws + 1804416);       // 320000*4 = 1280000
  unsigned long long* cand = (unsigned long long*)(ws + 3084416); // 8*4096*8 = 262144
  float* cbox   = (float*)(ws + 3346560);        // 4000*4*4 = 64000
  int*   cgid   = (int*)  (ws + 3410560);        // 4000*4
  float* cscore = (float*)(ws + 3426560);        // 4000*4   (end 3442560)

  hipMemsetAsync(d_ws, 0, 524416, stream);       // hist + cnt + tbin + maxbits

  k_score  <<<(BB*NN*4)/256, 256, 0, stream>>>(pconf, logitv, label, hist);
  k_thresh <<<BB, 256, 0, stream>>>(hist, tbin);
  k_compact<<<(BB*NN+255)/256, 256, 0, stream>>>(logitv, tbin, cnt, cand);
  k_rankemit<<<BB, 512, 0, stream>>>(cand, cnt, label, pboxes, out,
                                     cbox, cgid, cscore, maxbits);
  k_nms    <<<NGROUPS, 64, 0, stream>>>(cbox, cgid, cscore, maxbits, out + 7*MM);
}

// Round 4
// 238.251 us; speedup vs baseline: 1.2131x; 1.2131x over previous
//
#include <hip/hip_runtime.h>
#include <math.h>

#define BB 8
#define NN 40000
#define CC 80
#define TOPK 500
#define MM (BB*TOPK)          // 4000
#define NBINS 4096
#define BIN_LO (-8.0f)
#define BIN_SCALE 256.0f      // bins per unit -> covers [-8, 8)
#define CAP 4096
#define NGROUPS (CC*BB)       // 640
#define THR_CONF_F 0.05f
#define THR_NMS_F 0.5f

__device__ __forceinline__ int bin_of(float x){
  float f = (x - BIN_LO) * BIN_SCALE;
  int b = (int)floorf(f);
  b = b < 0 ? 0 : b;
  b = b > (NBINS-1) ? (NBINS-1) : b;
  return b;
}

// Kernel 1: 4 lanes per row, perfectly coalesced 64B-per-instruction reads.
// NO atomics (that was the 79us floor). Cross-lane argmax keeps first-max
// semantics via (==, idx<) tie-break; within-thread scan is index-increasing.
__global__ void k_score(const float* __restrict__ pconf,
                        float* __restrict__ logitv, int* __restrict__ label){
  int g   = blockIdx.x*256 + threadIdx.x;   // 1.28M threads total
  int row = g >> 2;
  int sub = g & 3;
  const float4* p = (const float4*)pconf + (size_t)row*20 + sub;
  float4 v0 = p[0], v1 = p[4], v2 = p[8], v3 = p[12], v4 = p[16];
  float best = -3.4e38f; int bi = 0;
  int c0 = sub*4;
  #define CHK(vv,it) { \
    int base = c0 + (it)*16; \
    if(vv.x>best){best=vv.x;bi=base+0;} \
    if(vv.y>best){best=vv.y;bi=base+1;} \
    if(vv.z>best){best=vv.z;bi=base+2;} \
    if(vv.w>best){best=vv.w;bi=base+3;} }
  CHK(v0,0) CHK(v1,1) CHK(v2,2) CHK(v3,3) CHK(v4,4)
  #undef CHK
  #pragma unroll
  for(int d=1; d<4; d<<=1){
    float ov = __shfl_xor(best, d, 64);
    int   oi = __shfl_xor(bi,   d, 64);
    if(ov > best || (ov == best && oi < bi)){ best = ov; bi = oi; }
  }
  if(sub == 0){
    logitv[row] = best; label[row] = bi;
  }
}

// Kernel 2: per-batch LDS histogram + parallel suffix-scan threshold.
// One block per batch. Replaces global-atomic hist AND the serial k_thresh.
__global__ void __launch_bounds__(1024)
k_histthresh(const float* __restrict__ logitv, int* __restrict__ tbin){
  int b = blockIdx.x;
  int t = threadIdx.x;
  __shared__ int h[NBINS];
  __shared__ int ss[1024];
  for(int i=t; i<NBINS; i+=1024) h[i] = 0;
  __syncthreads();
  const float4* lv4 = (const float4*)(logitv + (size_t)b*NN);
  for(int i=t; i<NN/4; i+=1024){
    float4 v = lv4[i];
    atomicAdd(&h[bin_of(v.x)], 1);
    atomicAdd(&h[bin_of(v.y)], 1);
    atomicAdd(&h[bin_of(v.z)], 1);
    atomicAdd(&h[bin_of(v.w)], 1);
  }
  __syncthreads();
  // 4 bins per thread -> chunk sums
  int c0 = t*4;
  int cs = h[c0] + h[c0+1] + h[c0+2] + h[c0+3];
  ss[t] = cs;
  __syncthreads();
  // inclusive suffix sum across 1024 chunks (Hillis-Steele from the right)
  for(int off=1; off<1024; off<<=1){
    int v = (t+off < 1024) ? ss[t+off] : 0;
    __syncthreads();
    ss[t] += v;
    __syncthreads();
  }
  int sufExcl = (t < 1023) ? ss[t+1] : 0;
  // unique crossing chunk: suffix before chunk < TOPK <= suffix incl chunk
  if(sufExcl < TOPK && sufExcl + cs >= TOPK){
    int cum = sufExcl; int tb = 0;
    for(int k=3; k>=0; k--){
      cum += h[c0+k];
      if(cum >= TOPK){ tb = c0+k; break; }
    }
    tb -= 2; if(tb < 0) tb = 0;   // 2-bin safety margin for f32 tie groups
    tbin[b] = tb;
  }
}

// Kernel 3: compact candidates (bin >= threshold). Correctly-rounded f32
// sigmoid (double exp) only for selected rows (~530/batch). Key:
// bits[48:16]=sigmoid f32 bits, bits[15:0]=65535-idx => desc sort = score
// desc, index asc == jax.lax.top_k ordering incl. f32 tie groups.
__global__ void k_compact(const float* __restrict__ logitv,
                          const int* __restrict__ tbin, int* __restrict__ cnt,
                          unsigned long long* __restrict__ cand){
  int row = blockIdx.x*256 + threadIdx.x;
  if(row >= BB*NN) return;
  int b = row / NN;
  float lg = logitv[row];
  if(bin_of(lg) >= tbin[b]){
    int pos = atomicAdd(&cnt[b], 1);
    if(pos < CAP){
      float t = (float)exp(-(double)lg);   // correctly-rounded f32 exp(-x)
      float s = 1.0f/(1.0f+t);             // f32 add + f32 div
      unsigned int sb = __float_as_uint(s);
      int idx = row - b*NN;
      cand[(size_t)b*CAP + pos] =
        ((unsigned long long)sb << 16) | (unsigned long long)(65535 - idx);
    }
  }
}

// Kernel 4: O(n^2) rank-and-emit (n ~ 530). Keys unique -> rank is a
// permutation; thread with rank<500 emits to output slot 'rank' directly.
__global__ void __launch_bounds__(512)
k_rankemit(const unsigned long long* __restrict__ cand, const int* __restrict__ cnt,
           const int* __restrict__ label, const float* __restrict__ pboxes,
           float* __restrict__ out,
           float* __restrict__ cbox, int* __restrict__ cgid,
           float* __restrict__ cscore, int* __restrict__ maxbits){
  int b = blockIdx.x;
  __shared__ unsigned long long keys[CAP];
  int n = cnt[b]; if(n > CAP) n = CAP;
  for(int i=threadIdx.x; i<n; i+=512) keys[i] = cand[(size_t)b*CAP + i];
  __syncthreads();
  for(int i=threadIdx.x; i<n; i+=512){
    unsigned long long ki = keys[i];
    int rank = 0;
    for(int j=0; j<n; j++) rank += (keys[j] > ki) ? 1 : 0;
    if(rank < TOPK){
      int idx = 65535 - (int)(ki & 0xFFFFULL);
      int row = b*NN + idx;
      float s = __uint_as_float((unsigned int)(ki >> 16));
      int lab = label[row];
      float4 bv = *(const float4*)(pboxes + (size_t)row*4);
      int m = b*TOPK + rank;
      out[m] = (float)b;                       // ids_batch1
      float* ob = out + MM + (size_t)m*4;      // p_boxes1
      ob[0]=bv.x; ob[1]=bv.y; ob[2]=bv.z; ob[3]=bv.w;
      out[5*MM + m] = (float)lab;              // p_labels1
      out[6*MM + m] = s;                       // p_scores1
      cbox[m*4+0]=bv.x; cbox[m*4+1]=bv.y; cbox[m*4+2]=bv.z; cbox[m*4+3]=bv.w;
      cgid[m] = lab*BB + b;                    // ref key = label*B + batch
      cscore[m] = s;
      float mx = fmaxf(fmaxf(bv.x,bv.y), fmaxf(bv.z,bv.w));
      atomicMax(maxbits, __float_as_int(mx));  // all-positive max -> int cmp ok
    }
  }
}

// Kernel 5: per-(label,batch)-group greedy NMS, one wave per group. Groups are
// batch-pure: only scan this batch's 500 slots (8 iterations).
__global__ void __launch_bounds__(64)
k_nms(const float* __restrict__ cbox, const int* __restrict__ cgid,
      const float* __restrict__ cscore, const int* __restrict__ maxbits,
      float* __restrict__ out_keep){
  int g = blockIdx.x;
  int lane = threadIdx.x;
  __shared__ float bx[TOPK][4];
  __shared__ float area[TOPK];
  __shared__ int   mid[TOPK];
  __shared__ unsigned char keepf[TOPK];
  float mc  = __int_as_float(*maxbits);
  float off = (float)g * (mc + 1.0f);
  int b = g & (BB-1);                    // g = lab*BB + b
  int lo = b*TOPK, hi = lo + TOPK;

  int count = 0;
  for(int base=lo; base<hi; base+=64){
    int m = base + lane;
    bool match = (m < hi) && (cgid[m] == g);
    unsigned long long mk = __ballot(match);
    if(match){
      int p = count + __popcll(mk & ((1ULL<<lane)-1ULL));
      float x1 = cbox[m*4+0] + off;
      float y1 = cbox[m*4+1] + off;
      float x2 = cbox[m*4+2] + off;
      float y2 = cbox[m*4+3] + off;
      bx[p][0]=x1; bx[p][1]=y1; bx[p][2]=x2; bx[p][3]=y2;
      area[p] = (x2-x1)*(y2-y1);         // area of OFFSET box, like ref
      mid[p] = m;
      keepf[p] = (cscore[m] > THR_CONF_F) ? 1 : 0;
    }
    count += __popcll(mk);
  }
  __syncthreads();

  for(int i=0; i<count; i++){
    if(keepf[i]){
      float ix1=bx[i][0], iy1=bx[i][1], ix2=bx[i][2], iy2=bx[i][3], ia=area[i];
      for(int j=i+1+lane; j<count; j+=64){
        if(keepf[j]){
          float lx = fmaxf(ix1, bx[j][0]);
          float ly = fmaxf(iy1, bx[j][1]);
          float rx = fminf(ix2, bx[j][2]);
          float ry = fminf(iy2, bx[j][3]);
          float w = fmaxf(rx-lx, 0.0f), h = fmaxf(ry-ly, 0.0f);
          float inter = w*h;
          float uni = ia + area[j] - inter;     // (a_i + a_j) - inter, ref order
          float iou = inter / fmaxf(uni, 1e-9f);
          if(iou > THR_NMS_F) keepf[j] = 0;
        }
      }
    }
    __syncthreads();
  }
  for(int p=lane; p<count; p+=64)
    out_keep[mid[p]] = keepf[p] ? 1.0f : 0.0f;
}

extern "C" void kernel_launch(void* const* d_in, const int* in_sizes, int n_in,
                              void* d_out, int out_size, void* d_ws, size_t ws_size,
                              hipStream_t stream) {
  const float* pconf  = (const float*)d_in[0];
  const float* pboxes = (const float*)d_in[1];
  float* out = (float*)d_out;
  char* ws = (char*)d_ws;

  // ws layout (bytes)
  int* cnt     = (int*)(ws + 0);                 // 8*4 = 32
  int* maxbits = (int*)(ws + 32);                // 4
  int* tbin    = (int*)(ws + 64);                // 8*4
  float* logitv  = (float*)(ws + 128);           // 320000*4 = 1280000
  int*   label   = (int*)  (ws + 1280128);       // 320000*4 = 1280000
  unsigned long long* cand = (unsigned long long*)(ws + 2560128); // 8*4096*8
  float* cbox   = (float*)(ws + 2822272);        // 4000*4*4 = 64000
  int*   cgid   = (int*)  (ws + 2886272);        // 4000*4
  float* cscore = (float*)(ws + 2902272);        // 4000*4   (end 2918272)

  hipMemsetAsync(ws, 0, 64, stream);             // cnt + maxbits only

  k_score     <<<(BB*NN*4)/256, 256, 0, stream>>>(pconf, logitv, label);
  k_histthresh<<<BB, 1024, 0, stream>>>(logitv, tbin);
  k_compact   <<<(BB*NN+255)/256, 256, 0, stream>>>(logitv, tbin, cnt, cand);
  k_rankemit  <<<BB, 512, 0, stream>>>(cand, cnt, label, pboxes, out,
                                       cbox, cgid, cscore, maxbits);
  k_nms       <<<NGROUPS, 64, 0, stream>>>(cbox, cgid, cscore, maxbits, out + 7*MM);
}

// Round 6
// 191.006 us; speedup vs baseline: 1.5132x; 1.2473x over previous
//
#include <hip/hip_runtime.h>
#include <math.h>

#define BB 8
#define NN 40000
#define CC 80
#define TOPK 500
#define MM (BB*TOPK)          // 4000
#define NBINS 4096
#define BIN_LO (-8.0f)
#define BIN_SCALE 256.0f      // bins per unit -> covers [-8, 8)
#define CAP 4096
#define NGROUPS (CC*BB)       // 640
#define THR_CONF_F 0.05f
#define THR_NMS_F 0.5f

__device__ __forceinline__ int bin_of(float x){
  float f = (x - BIN_LO) * BIN_SCALE;
  int b = (int)floorf(f);
  b = b < 0 ? 0 : b;
  b = b > (NBINS-1) ? (NBINS-1) : b;
  return b;
}

// Kernel 1: 4 lanes per row, coalesced 64B-per-instruction reads, no atomics.
// Cross-lane argmax keeps first-max semantics via (==, idx<) tie-break.
__global__ void k_score(const float* __restrict__ pconf,
                        float* __restrict__ logitv, int* __restrict__ label){
  int g   = blockIdx.x*256 + threadIdx.x;   // 1.28M threads total
  int row = g >> 2;
  int sub = g & 3;
  const float4* p = (const float4*)pconf + (size_t)row*20 + sub;
  float4 v0 = p[0], v1 = p[4], v2 = p[8], v3 = p[12], v4 = p[16];
  float best = -3.4e38f; int bi = 0;
  int c0 = sub*4;
  #define CHK(vv,it) { \
    int base = c0 + (it)*16; \
    if(vv.x>best){best=vv.x;bi=base+0;} \
    if(vv.y>best){best=vv.y;bi=base+1;} \
    if(vv.z>best){best=vv.z;bi=base+2;} \
    if(vv.w>best){best=vv.w;bi=base+3;} }
  CHK(v0,0) CHK(v1,1) CHK(v2,2) CHK(v3,3) CHK(v4,4)
  #undef CHK
  #pragma unroll
  for(int d=1; d<4; d<<=1){
    float ov = __shfl_xor(best, d, 64);
    int   oi = __shfl_xor(bi,   d, 64);
    if(ov > best || (ov == best && oi < bi)){ best = ov; bi = oi; }
  }
  if(sub == 0){
    logitv[row] = best; label[row] = bi;
  }
}

// Kernel 2 (fused): per-batch LDS histogram -> parallel suffix-scan threshold
// -> compact (bin >= tbin) with correctly-rounded f32 sigmoid (double exp,
// only ~530 rows/batch) -> O(n^2) rank -> emit outputs + NMS scratch.
// Key: bits[48:16]=sigmoid f32 bits (positive -> unsigned-monotone),
// bits[15:0]=65535-idx => rank by key desc == score desc, index asc
// == jax.lax.top_k ordering incl. f32 tie groups.
__global__ void __launch_bounds__(1024)
k_select(const float* __restrict__ logitv, const int* __restrict__ label,
         const float* __restrict__ pboxes,
         float* __restrict__ out,
         float* __restrict__ cbox, int* __restrict__ cgid,
         float* __restrict__ cscore, int* __restrict__ maxval){
  int b = blockIdx.x;
  int t = threadIdx.x;
  __shared__ int h[NBINS];
  __shared__ int ss[1024];
  __shared__ unsigned long long keys[CAP];
  __shared__ int stbin, scnt, smax;
  for(int i=t; i<NBINS; i+=1024) h[i] = 0;
  if(t==0){ scnt = 0; smax = 0; }   // true max positive -> 0-init safe
  __syncthreads();

  // --- histogram of this batch's logits ---
  const float4* lv4 = (const float4*)(logitv + (size_t)b*NN);
  for(int i=t; i<NN/4; i+=1024){
    float4 v = lv4[i];
    atomicAdd(&h[bin_of(v.x)], 1);
    atomicAdd(&h[bin_of(v.y)], 1);
    atomicAdd(&h[bin_of(v.z)], 1);
    atomicAdd(&h[bin_of(v.w)], 1);
  }
  __syncthreads();

  // --- threshold bin: suffix count >= TOPK, 2-bin safety margin ---
  int c0 = t*4;
  int cs = h[c0] + h[c0+1] + h[c0+2] + h[c0+3];
  ss[t] = cs;
  __syncthreads();
  for(int off=1; off<1024; off<<=1){
    int v = (t+off < 1024) ? ss[t+off] : 0;
    __syncthreads();
    ss[t] += v;
    __syncthreads();
  }
  int sufExcl = (t < 1023) ? ss[t+1] : 0;
  if(sufExcl < TOPK && sufExcl + cs >= TOPK){
    int cum = sufExcl; int tb = 0;
    for(int k=3; k>=0; k--){
      cum += h[c0+k];
      if(cum >= TOPK){ tb = c0+k; break; }
    }
    tb -= 2; if(tb < 0) tb = 0;
    stbin = tb;
  }
  __syncthreads();
  int tb = stbin;

  // --- compact candidates into LDS ---
  const float* lv = logitv + (size_t)b*NN;
  for(int idx=t; idx<NN; idx+=1024){
    float lg = lv[idx];
    if(bin_of(lg) >= tb){
      int pos = atomicAdd(&scnt, 1);
      if(pos < CAP){
        float e = (float)exp(-(double)lg);   // correctly-rounded f32 exp(-x)
        float s = 1.0f/(1.0f+e);             // f32 add + f32 div
        keys[pos] = ((unsigned long long)__float_as_uint(s) << 16)
                  | (unsigned long long)(65535 - idx);
      }
    }
  }
  __syncthreads();
  int n = scnt; if(n > CAP) n = CAP;

  // --- rank (keys unique -> permutation) + emit ---
  for(int i=t; i<n; i+=1024){
    unsigned long long ki = keys[i];
    int rank = 0;
    for(int j=0; j<n; j++) rank += (keys[j] > ki) ? 1 : 0;
    if(rank < TOPK){
      int idx = 65535 - (int)(ki & 0xFFFFULL);
      int row = b*NN + idx;
      float s = __uint_as_float((unsigned int)(ki >> 16));
      int lab = label[row];
      float4 bv = *(const float4*)(pboxes + (size_t)row*4);
      int m = b*TOPK + rank;
      out[m] = (float)b;                       // ids_batch1
      float* ob = out + MM + (size_t)m*4;      // p_boxes1
      ob[0]=bv.x; ob[1]=bv.y; ob[2]=bv.z; ob[3]=bv.w;
      out[5*MM + m] = (float)lab;              // p_labels1
      out[6*MM + m] = s;                       // p_scores1
      cbox[m*4+0]=bv.x; cbox[m*4+1]=bv.y; cbox[m*4+2]=bv.z; cbox[m*4+3]=bv.w;
      cgid[m] = lab*BB + b;                    // ref key = label*B + batch
      cscore[m] = s;
      float mx = fmaxf(fmaxf(bv.x,bv.y), fmaxf(bv.z,bv.w));
      atomicMax(&smax, __float_as_int(mx));    // positive max -> int cmp ok
    }
  }
  __syncthreads();
  if(t==0) maxval[b] = smax;
}

// Kernel 3: per-(label,batch)-group greedy NMS, one wave per group. Cross-group
// IoU exactly 0 (offset gap), so global greedy == per-group greedy in
// within-group flat order. Groups are batch-pure: scan only this batch's 500.
__global__ void __launch_bounds__(64)
k_nms(const float* __restrict__ cbox, const int* __restrict__ cgid,
      const float* __restrict__ cscore, const int* __restrict__ maxval,
      float* __restrict__ out_keep){
  int g = blockIdx.x;
  int lane = threadIdx.x;
  __shared__ float bx[TOPK][4];
  __shared__ float area[TOPK];
  __shared__ int   mid[TOPK];
  __shared__ unsigned char keepf[TOPK];
  int mb = maxval[0];
  #pragma unroll
  for(int k=1;k<BB;k++) mb = max(mb, maxval[k]); // positive floats: int cmp ok
  float mc  = __int_as_float(mb);
  float off = (float)g * (mc + 1.0f);
  int b = g & (BB-1);                    // g = lab*BB + b
  int lo = b*TOPK, hi = lo + TOPK;

  int count = 0;
  for(int base=lo; base<hi; base+=64){
    int m = base + lane;
    bool match = (m < hi) && (cgid[m] == g);
    unsigned long long mk = __ballot(match);
    if(match){
      int p = count + __popcll(mk & ((1ULL<<lane)-1ULL));
      float x1 = cbox[m*4+0] + off;
      float y1 = cbox[m*4+1] + off;
      float x2 = cbox[m*4+2] + off;
      float y2 = cbox[m*4+3] + off;
      bx[p][0]=x1; bx[p][1]=y1; bx[p][2]=x2; bx[p][3]=y2;
      area[p] = (x2-x1)*(y2-y1);         // area of OFFSET box, like ref
      mid[p] = m;
      keepf[p] = (cscore[m] > THR_CONF_F) ? 1 : 0;
    }
    count += __popcll(mk);
  }
  __syncthreads();

  for(int i=0; i<count; i++){
    if(keepf[i]){
      float ix1=bx[i][0], iy1=bx[i][1], ix2=bx[i][2], iy2=bx[i][3], ia=area[i];
      for(int j=i+1+lane; j<count; j+=64){
        if(keepf[j]){
          float lx = fmaxf(ix1, bx[j][0]);
          float ly = fmaxf(iy1, bx[j][1]);
          float rx = fminf(ix2, bx[j][2]);
          float ry = fminf(iy2, bx[j][3]);
          float w = fmaxf(rx-lx, 0.0f), h = fmaxf(ry-ly, 0.0f);
          float inter = w*h;
          float uni = ia + area[j] - inter;     // (a_i + a_j) - inter, ref order
          float iou = inter / fmaxf(uni, 1e-9f);
          if(iou > THR_NMS_F) keepf[j] = 0;
        }
      }
    }
    __syncthreads();
  }
  for(int p=lane; p<count; p+=64)
    out_keep[mid[p]] = keepf[p] ? 1.0f : 0.0f;
}

extern "C" void kernel_launch(void* const* d_in, const int* in_sizes, int n_in,
                              void* d_out, int out_size, void* d_ws, size_t ws_size,
                              hipStream_t stream) {
  const float* pconf  = (const float*)d_in[0];
  const float* pboxes = (const float*)d_in[1];
  float* out = (float*)d_out;
  char* ws = (char*)d_ws;

  // ws layout (bytes) — everything written before read, no memset needed
  float* logitv  = (float*)(ws + 0);             // 320000*4 = 1280000
  int*   label   = (int*)  (ws + 1280000);       // 320000*4 = 1280000
  float* cbox    = (float*)(ws + 2560000);       // 4000*4*4 = 64000
  int*   cgid    = (int*)  (ws + 2624000);       // 4000*4
  float* cscore  = (float*)(ws + 2640000);       // 4000*4
  int*   maxval  = (int*)  (ws + 2656000);       // 8*4      (end 2656032)

  k_score <<<(BB*NN*4)/256, 256, 0, stream>>>(pconf, logitv, label);
  k_select<<<BB, 1024, 0, stream>>>(logitv, label, pboxes, out,
                                    cbox, cgid, cscore, maxval);
  k_nms   <<<NGROUPS, 64, 0, stream>>>(cbox, cgid, cscore, maxval, out + 7*MM);
}